// Round 7
// baseline (350.413 us; speedup 1.0000x reference)
//
#include <hip/hip_runtime.h>

typedef unsigned short u16;
typedef unsigned int u32;
typedef _Float16 f16;
typedef __attribute__((ext_vector_type(8))) _Float16 half8;
typedef __attribute__((ext_vector_type(2))) __fp16 fp16x2;
typedef __attribute__((ext_vector_type(4))) float float4_;
typedef __attribute__((ext_vector_type(4))) unsigned short ushort4_;
typedef __attribute__((ext_vector_type(4))) unsigned int u32x4;

union hu { f16 h; u16 u; };

__device__ __forceinline__ u32 pkrtz(float a, float b) {
    fp16x2 t = __builtin_amdgcn_cvt_pkrtz(a, b);
    union { fp16x2 h; u32 u; } cv; cv.h = t;
    return cv.u;
}

// ---------- async global->LDS, 16B/lane ----------
__device__ __forceinline__ void gl16(const u16* g, u16* l) {
    __builtin_amdgcn_global_load_lds(
        (const __attribute__((address_space(1))) void*)g,
        (__attribute__((address_space(3))) void*)l, 16, 0, 0);
}

#define Bsz 8
#define Tsz 4096
#define Csz 512
#define Usz 512
#define NG  1536           // 3U
#define KK  1024           // 2 taps * C
#define MM  32768          // B*T
#define NCH 256            // scan chunks (4 blocks/CU in chunk kernels)
#define CHL 16             // chunk length (NCH*CHL = 4096)

// ---------- P0: inputs fp32 -> fp16 plane [8][4097][512], zero row at t=4096 ----------
__global__ void prep_a(const float* __restrict__ in, u16* __restrict__ A16) {
    int gid = blockIdx.x * 256 + threadIdx.x;       // 2,097,664 threads, 8 halves each
    int idx8 = gid * 8;
    int c8 = idx8 & 511;
    int row = idx8 >> 9;                            // b*4097 + t
    int b = (u32)row / 4097u;
    int t = row - b * 4097;
    u32x4 w;
    if (t == Tsz) {
        w = (u32x4)0;
    } else {
        const float* p = in + ((size_t)(b * Tsz + t) << 9) + c8;
        float4_ v0 = *(const float4_*)p;
        float4_ v1 = *(const float4_*)(p + 4);
        w.x = pkrtz(v0.x, v0.y); w.y = pkrtz(v0.z, v0.w);
        w.z = pkrtz(v1.x, v1.y); w.w = pkrtz(v1.z, v1.w);
    }
    *(u32x4*)(A16 + idx8) = w;
}

// ---------- P1: weights [K=1024][N=1536] fp32 -> transposed fp16 [N][K] ----------
// LDS 64x64 transpose: coalesced fp32 reads, 8B/lane coalesced u16 writes.
__global__ void prep_k(const float* __restrict__ kern, u16* __restrict__ KT) {
    __shared__ u16 t[64][70];                 // 70: spread banks on both phases
    const int k0 = blockIdx.x * 64;           // 16 blocks
    const int n0 = blockIdx.y * 64;           // 24 blocks
    const int tid = threadIdx.x;              // 256
    #pragma unroll
    for (int it = 0; it < 16; ++it) {
        int s = it * 256 + tid;
        int r = s >> 6;                        // k within tile
        int c = s & 63;                        // n within tile (coalesced)
        float v = kern[(size_t)(k0 + r) * NG + n0 + c];
        hu cv; cv.h = (f16)v;                  // RNE
        t[c][r] = cv.u;
    }
    __syncthreads();
    #pragma unroll
    for (int it = 0; it < 4; ++it) {
        int s = it * 256 + tid;
        int n = s >> 4;                        // row of KT tile
        int kq = (s & 15) * 4;                 // 4 u16 per lane, coalesced
        ushort4_ w;
        w.x = t[n][kq]; w.y = t[n][kq + 1]; w.z = t[n][kq + 2]; w.w = t[n][kq + 3];
        *(ushort4_*)(KT + (size_t)(n0 + n) * KK + k0 + kq) = w;
    }
}

// ---------- GEMM (R0-proven core): gates = A'*K', fp16 MFMA, BK=64, XOR-swizzled LDS ----------
// R6 measured: 127.7us, MfmaUtil 38-39%, FETCH 85MB, 0 conflicts -> at the
// 2-barrier-structure ceiling (~807 TF vs ~900 structural). 8-phase ports lost
// twice (R3/R5) -> schedule surgery retired. Only change vs R6: launch_bounds
// (256,5): LDS 32KB x5 = exactly 160KiB/CU, VGPR 64 << 102-cap -> a 5th
// co-resident block of free TLP against the per-K-step barrier drain.
__global__ __launch_bounds__(256, 5) void gemm_gates(
    const u16* __restrict__ A16, const u16* __restrict__ KT,
    const float* __restrict__ bias,
    u16* __restrict__ X, u16* __restrict__ F, float* __restrict__ O)
{
    // Tiles [128 rows][64 halves]; 16B chunk c of row r stored at position c ^ (r&7)
    // -> every ds_read_b128 hits the 8-words/bank wave64 floor (0 conflicts, R0/R6).
    __shared__ u16 lA[8192], lB[8192];

    const int tid  = threadIdx.x;
    const int lane = tid & 63;
    const int wave = tid >> 6;

    // bijective XCD swizzle: 3072 wg = 8 XCDs x 384; nb-minor within an XCD so
    // 12 consecutive blocks share one 256KB A tile (L2-hit x12) and KT (3MB)
    // stays L2-resident per XCD. Proven: FETCH 278MB -> 85MB.
    const int orig = blockIdx.x;
    const int wg = (orig & 7) * 384 + (orig >> 3);
    const int nb = wg % 12;
    const int mb = wg / 12;
    const int m0 = mb * 128;
    const int n0 = nb * 128;
    const int b  = m0 >> 12;            // 128 | 4096 -> block never straddles batches
    const int t0 = m0 & 4095;
    const int arow0 = b * (Tsz + 1) + t0;

    float4_ acc[4][4];
    #pragma unroll
    for (int i = 0; i < 4; ++i)
        #pragma unroll
        for (int j = 0; j < 4; ++j) acc[i][j] = (float4_)0.0f;

    const int wm = (wave >> 1) * 64;
    const int wn = (wave & 1) * 64;
    const int ar = wm + (lane & 15);
    const int br = wn + (lane & 15);
    const int q  = lane >> 4;           // k-quad
    const int swz = lane & 7;           // == ar&7 == br&7 (wm,wn multiples of 64)

    for (int kc = 0; kc < KK; kc += 64) {
        __syncthreads();   // protect LDS from previous iteration's readers
        const int tap = kc >> 9;
        const int kin = kc & 511;
        const int ab = arow0 + tap;
        // --- A staging: 128x64 fp16 = 16KB, 4 gl16 iters, XOR-permuted source ---
        #pragma unroll
        for (int it = 0; it < 4; ++it) {
            const int s = it * 256 + tid;          // chunk slot [0,1024)
            const int row = s >> 3, p = s & 7;
            const int c = p ^ (row & 7);
            gl16(A16 + (((size_t)(ab + row)) << 9) + kin + c * 8, lA + (s - lane) * 8);
        }
        // --- B staging: 128x64 fp16 = 16KB ---
        #pragma unroll
        for (int it = 0; it < 4; ++it) {
            const int s = it * 256 + tid;
            const int row = s >> 3, p = s & 7;
            const int c = p ^ (row & 7);
            gl16(KT + (((size_t)(n0 + row)) << 10) + kc + c * 8, lB + (s - lane) * 8);
        }
        __syncthreads();   // staging complete (barrier drains vmcnt)

        #pragma unroll
        for (int s2 = 0; s2 < 2; ++s2) {
            half8 fa[4], fb[4];
            const int cc = (s2 * 4 + q) ^ swz;     // swizzled chunk position
            #pragma unroll
            for (int i = 0; i < 4; ++i) {
                fa[i] = *(const half8*)(lA + (ar + i * 16) * 64 + cc * 8);
                fb[i] = *(const half8*)(lB + (br + i * 16) * 64 + cc * 8);
            }
            #pragma unroll
            for (int mi = 0; mi < 4; ++mi)
                #pragma unroll
                for (int ni = 0; ni < 4; ++ni)
                    acc[mi][ni] = __builtin_amdgcn_mfma_f32_16x16x32_f16(fa[mi], fb[ni], acc[mi][ni], 0, 0, 0);
        }
    }

    // epilogue: bias + activation. Plane uniform per block (128 | 512).
    const int plane = nb >> 2;   // 0=X,1=F,2=O
    const int rq = q * 4;
    const int cl = lane & 15;
    #pragma unroll
    for (int mi = 0; mi < 4; ++mi)
        #pragma unroll
        for (int ni = 0; ni < 4; ++ni) {
            const int gm = m0 + wm + mi * 16 + rq;
            const int gn = n0 + wn + ni * 16 + cl;
            const float bv = bias[gn];
            const int cp = gn & 511;
            #pragma unroll
            for (int r2 = 0; r2 < 4; ++r2) {
                float v = acc[mi][ni][r2] + bv;
                if (plane == 0) {
                    float res = 1.0f - 2.0f / (__expf(2.0f * v) + 1.0f);   // tanh, overflow-safe
                    hu cv; cv.h = (f16)res;
                    X[(size_t)(gm + r2) * Usz + cp] = cv.u;
                } else if (plane == 1) {
                    float res = 1.0f / (1.0f + __expf(-v));                // sigmoid, overflow-safe
                    hu cv; cv.h = (f16)res;
                    F[(size_t)(gm + r2) * Usz + cp] = cv.u;
                } else {
                    float res = 1.0f / (1.0f + __expf(-v));
                    O[(size_t)(gm + r2) * Usz + cp] = res;
                }
            }
        }
}

__device__ __forceinline__ float4_ x4(const u16* p) {
    ushort4_ xr = *(const ushort4_*)p;
    float4_ xv;
    #pragma unroll
    for (int j = 0; j < 4; ++j) { hu cv; cv.u = xr[j]; xv[j] = (float)cv.h; }
    return xv;
}

__device__ __forceinline__ float4_ cvt4(ushort4_ xr) {
    float4_ xv;
    #pragma unroll
    for (int j = 0; j < 4; ++j) { hu cv; cv.u = xr[j]; xv[j] = (float)cv.h; }
    return xv;
}

// ---------- S1: per-chunk composites A=prod f, B=chunk applied to c=0 ----------
// NCH=256 -> 1024 blocks (4/CU, 4 waves/SIMD); next-iter loads prefetched so the
// f/x loads for step i+1 issue before step i's dependent FMA chain (G7).
__global__ __launch_bounds__(256) void scan_chunk(
    const u16* __restrict__ F, const u16* __restrict__ X,
    float* __restrict__ CA, float* __restrict__ CB) {
    int g = blockIdx.x * 256 + threadIdx.x;     // 262144 = B*NCH*U/4
    int u4 = (g & 127) * 4;
    int bc = g >> 7;                             // b*NCH + ch
    size_t base = (size_t)bc * CHL * Usz + u4;
    float4_ c = (float4_)0.0f, A = (float4_)1.0f;
    ushort4_ fcur = *(const ushort4_*)(F + base);
    ushort4_ xcur = *(const ushort4_*)(X + base);
    #pragma unroll
    for (int i = 0; i < CHL; ++i) {
        ushort4_ fnx = fcur, xnx = xcur;
        if (i + 1 < CHL) {
            fnx = *(const ushort4_*)(F + base + (size_t)(i + 1) * Usz);
            xnx = *(const ushort4_*)(X + base + (size_t)(i + 1) * Usz);
        }
        float4_ fv = cvt4(fcur);
        float4_ xv = cvt4(xcur);
        c = fv * c + (1.0f - fv) * xv;
        A = A * fv;
        fcur = fnx; xcur = xnx;
    }
    *(float4_*)(CA + (size_t)bc * Usz + u4) = A;
    *(float4_*)(CB + (size_t)bc * Usz + u4) = c;
}

// ---------- S2: sequential prefix across chunks -> chunk-start carries ----------
// loads are c-independent (address-only) -> unrolled window pipelines them.
__global__ __launch_bounds__(256) void scan_prefix(
    const float* __restrict__ CA, const float* __restrict__ CB,
    float* __restrict__ CS) {
    int g = blockIdx.x * 256 + threadIdx.x;     // 4096 = B*U
    int u = g & 511;
    int b = g >> 9;
    float c = 0.0f;
    #pragma unroll 8
    for (int ch = 0; ch < NCH; ++ch) {
        int idx = (b * NCH + ch) * Usz + u;
        CS[idx] = c;
        c = CA[idx] * c + CB[idx];
    }
}

// ---------- S3: re-scan chunks with carry, h = sigmoid(o)*c (O in-place in out) ----------
__global__ __launch_bounds__(256) void scan_final(
    const u16* __restrict__ F, const u16* __restrict__ X,
    const float* __restrict__ CS, float* __restrict__ out) {
    int g = blockIdx.x * 256 + threadIdx.x;     // 262144
    int u4 = (g & 127) * 4;
    int bc = g >> 7;
    size_t base = (size_t)bc * CHL * Usz + u4;
    float4_ c = *(const float4_*)(CS + (size_t)bc * Usz + u4);
    ushort4_ fcur = *(const ushort4_*)(F + base);
    ushort4_ xcur = *(const ushort4_*)(X + base);
    #pragma unroll
    for (int i = 0; i < CHL; ++i) {
        ushort4_ fnx = fcur, xnx = xcur;
        if (i + 1 < CHL) {
            fnx = *(const ushort4_*)(F + base + (size_t)(i + 1) * Usz);
            xnx = *(const ushort4_*)(X + base + (size_t)(i + 1) * Usz);
        }
        float4_ fv = cvt4(fcur);
        float4_ xv = cvt4(xcur);
        c = fv * c + (1.0f - fv) * xv;
        float4_ ov = *(const float4_*)(out + base + (size_t)i * Usz);  // read O before overwrite
        *(float4_*)(out + base + (size_t)i * Usz) = ov * c;
        fcur = fnx; xcur = xnx;
    }
}

extern "C" void kernel_launch(void* const* d_in, const int* in_sizes, int n_in,
                              void* d_out, int out_size, void* d_ws, size_t ws_size,
                              hipStream_t stream) {
    const float* in   = (const float*)d_in[0];   // [8,4096,512] fp32
    const float* kern = (const float*)d_in[1];   // [2,512,1536] fp32
    const float* bias = (const float*)d_in[2];   // [1536] fp32
    float* out = (float*)d_out;                  // [8,4096,512] fp32
    char* ws = (char*)d_ws;

    // workspace layout (~99 MB; known budget >= 110,102,528)
    const size_t A16_B  = (size_t)Bsz * (Tsz + 1) * Csz * 2;   // 33,562,624
    const size_t OFF_KT = A16_B;
    const size_t OFF_F  = OFF_KT + (size_t)NG * KK * 2;        // 36,708,352
    const size_t OFF_X  = OFF_F + (size_t)MM * Usz * 2;        // 70,262,784
    const size_t NEED   = OFF_X + (size_t)MM * Usz * 2;        // 103,817,216

    if (ws_size < NEED) return;   // guard: fail-with-poison instead of OOB fault

    u16*   A16 = (u16*)ws;
    u16*   KT  = (u16*)(ws + OFF_KT);
    u16*   Fh  = (u16*)(ws + OFF_F);
    u16*   Xb  = (u16*)(ws + OFF_X);
    // scan scratch (12 MB @ NCH=256) aliases the A16 region: A16 is dead once
    // gemm_gates completes, and all launches are stream-ordered (graph replay
    // preserves order; prep_a fully rewrites the region at the start of every replay).
    const size_t CH = (size_t)Bsz * NCH * Usz;   // floats per composite plane
    float* CA = (float*)ws;
    float* CB = CA + CH;
    float* CS = CB + CH;

    prep_a<<<(int)(A16_B / 16 / 256), 256, 0, stream>>>(in, A16);
    prep_k<<<dim3(KK / 64, NG / 64), 256, 0, stream>>>(kern, KT);
    gemm_gates<<<(MM / 128) * (NG / 128), 256, 0, stream>>>(A16, KT, bias, Xb, Fh, out);
    scan_chunk<<<Bsz * NCH * Usz / 4 / 256, 256, 0, stream>>>(Fh, Xb, CA, CB);
    scan_prefix<<<Bsz * Usz / 256, 256, 0, stream>>>(CA, CB, CS);
    scan_final<<<Bsz * NCH * Usz / 4 / 256, 256, 0, stream>>>(Fh, Xb, CS, out);
}

// Round 8
// 302.721 us; speedup vs baseline: 1.1575x; 1.1575x over previous
//
#include <hip/hip_runtime.h>

typedef unsigned short u16;
typedef unsigned int u32;
typedef _Float16 f16;
typedef __attribute__((ext_vector_type(8))) _Float16 half8;
typedef __attribute__((ext_vector_type(2))) __fp16 fp16x2;
typedef __attribute__((ext_vector_type(4))) float float4_;
typedef __attribute__((ext_vector_type(4))) unsigned short ushort4_;
typedef __attribute__((ext_vector_type(4))) unsigned int u32x4;

union hu { f16 h; u16 u; };

__device__ __forceinline__ u32 pkrtz(float a, float b) {
    fp16x2 t = __builtin_amdgcn_cvt_pkrtz(a, b);
    union { fp16x2 h; u32 u; } cv; cv.h = t;
    return cv.u;
}

// ---------- async global->LDS, 16B/lane ----------
__device__ __forceinline__ void gl16(const u16* g, u16* l) {
    __builtin_amdgcn_global_load_lds(
        (const __attribute__((address_space(1))) void*)g,
        (__attribute__((address_space(3))) void*)l, 16, 0, 0);
}

#define Bsz 8
#define Tsz 4096
#define Csz 512
#define Usz 512
#define NG  1536           // 3U
#define KK  1024           // 2 taps * C
#define MM  32768          // B*T
#define NCH 256            // scan chunks (4 blocks/CU in chunk kernels)
#define CHL 16             // chunk length (NCH*CHL = 4096)

// ---------- P0: inputs fp32 -> fp16 plane [8][4097][512], zero row at t=4096 ----------
__global__ void prep_a(const float* __restrict__ in, u16* __restrict__ A16) {
    int gid = blockIdx.x * 256 + threadIdx.x;       // 2,097,664 threads, 8 halves each
    int idx8 = gid * 8;
    int c8 = idx8 & 511;
    int row = idx8 >> 9;                            // b*4097 + t
    int b = (u32)row / 4097u;
    int t = row - b * 4097;
    u32x4 w;
    if (t == Tsz) {
        w = (u32x4)0;
    } else {
        const float* p = in + ((size_t)(b * Tsz + t) << 9) + c8;
        float4_ v0 = *(const float4_*)p;
        float4_ v1 = *(const float4_*)(p + 4);
        w.x = pkrtz(v0.x, v0.y); w.y = pkrtz(v0.z, v0.w);
        w.z = pkrtz(v1.x, v1.y); w.w = pkrtz(v1.z, v1.w);
    }
    *(u32x4*)(A16 + idx8) = w;
}

// ---------- P1: weights [K=1024][N=1536] fp32 -> transposed fp16 [N][K] ----------
// LDS 64x64 transpose: coalesced fp32 reads, 8B/lane coalesced u16 writes.
__global__ void prep_k(const float* __restrict__ kern, u16* __restrict__ KT) {
    __shared__ u16 t[64][70];                 // 70: spread banks on both phases
    const int k0 = blockIdx.x * 64;           // 16 blocks
    const int n0 = blockIdx.y * 64;           // 24 blocks
    const int tid = threadIdx.x;              // 256
    #pragma unroll
    for (int it = 0; it < 16; ++it) {
        int s = it * 256 + tid;
        int r = s >> 6;                        // k within tile
        int c = s & 63;                        // n within tile (coalesced)
        float v = kern[(size_t)(k0 + r) * NG + n0 + c];
        hu cv; cv.h = (f16)v;                  // RNE
        t[c][r] = cv.u;
    }
    __syncthreads();
    #pragma unroll
    for (int it = 0; it < 4; ++it) {
        int s = it * 256 + tid;
        int n = s >> 4;                        // row of KT tile
        int kq = (s & 15) * 4;                 // 4 u16 per lane, coalesced
        ushort4_ w;
        w.x = t[n][kq]; w.y = t[n][kq + 1]; w.z = t[n][kq + 2]; w.w = t[n][kq + 3];
        *(ushort4_*)(KT + (size_t)(n0 + n) * KK + k0 + kq) = w;
    }
}

// ---------- GEMM (R6-proven core): gates = A'*K', fp16 MFMA, BK=64, XOR-swizzled LDS ----------
// R6 measured: 127.7us, MfmaUtil 38-39%, VGPR 64, FETCH 85MB, 0 conflicts.
// R7 lesson: __launch_bounds__(256,5) squeezed VGPR 64->48 and cost 52% (194us,
// MfmaUtil 23%) for +4% occupancy -- bound only to the occupancy you need (G1/G6).
// Keep (256,4). 8-phase schedule ports lost twice (R3/R5) -> schedule retired;
// this 2-barrier structure at ~807 TF is the keeper.
__global__ __launch_bounds__(256, 4) void gemm_gates(
    const u16* __restrict__ A16, const u16* __restrict__ KT,
    const float* __restrict__ bias,
    u16* __restrict__ X, u16* __restrict__ F, float* __restrict__ O)
{
    // Tiles [128 rows][64 halves]; 16B chunk c of row r stored at position c ^ (r&7)
    // -> every ds_read_b128 hits the 8-words/bank wave64 floor (0 conflicts, R0/R6).
    __shared__ u16 lA[8192], lB[8192];

    const int tid  = threadIdx.x;
    const int lane = tid & 63;
    const int wave = tid >> 6;

    // bijective XCD swizzle: 3072 wg = 8 XCDs x 384; nb-minor within an XCD so
    // 12 consecutive blocks share one 256KB A tile (L2-hit x12) and KT (3MB)
    // stays L2-resident per XCD. Proven: FETCH 278MB -> 85MB.
    const int orig = blockIdx.x;
    const int wg = (orig & 7) * 384 + (orig >> 3);
    const int nb = wg % 12;
    const int mb = wg / 12;
    const int m0 = mb * 128;
    const int n0 = nb * 128;
    const int b  = m0 >> 12;            // 128 | 4096 -> block never straddles batches
    const int t0 = m0 & 4095;
    const int arow0 = b * (Tsz + 1) + t0;

    float4_ acc[4][4];
    #pragma unroll
    for (int i = 0; i < 4; ++i)
        #pragma unroll
        for (int j = 0; j < 4; ++j) acc[i][j] = (float4_)0.0f;

    const int wm = (wave >> 1) * 64;
    const int wn = (wave & 1) * 64;
    const int ar = wm + (lane & 15);
    const int br = wn + (lane & 15);
    const int q  = lane >> 4;           // k-quad
    const int swz = lane & 7;           // == ar&7 == br&7 (wm,wn multiples of 64)

    for (int kc = 0; kc < KK; kc += 64) {
        __syncthreads();   // protect LDS from previous iteration's readers
        const int tap = kc >> 9;
        const int kin = kc & 511;
        const int ab = arow0 + tap;
        // --- A staging: 128x64 fp16 = 16KB, 4 gl16 iters, XOR-permuted source ---
        #pragma unroll
        for (int it = 0; it < 4; ++it) {
            const int s = it * 256 + tid;          // chunk slot [0,1024)
            const int row = s >> 3, p = s & 7;
            const int c = p ^ (row & 7);
            gl16(A16 + (((size_t)(ab + row)) << 9) + kin + c * 8, lA + (s - lane) * 8);
        }
        // --- B staging: 128x64 fp16 = 16KB ---
        #pragma unroll
        for (int it = 0; it < 4; ++it) {
            const int s = it * 256 + tid;
            const int row = s >> 3, p = s & 7;
            const int c = p ^ (row & 7);
            gl16(KT + (((size_t)(n0 + row)) << 10) + kc + c * 8, lB + (s - lane) * 8);
        }
        __syncthreads();   // staging complete (barrier drains vmcnt)

        #pragma unroll
        for (int s2 = 0; s2 < 2; ++s2) {
            half8 fa[4], fb[4];
            const int cc = (s2 * 4 + q) ^ swz;     // swizzled chunk position
            #pragma unroll
            for (int i = 0; i < 4; ++i) {
                fa[i] = *(const half8*)(lA + (ar + i * 16) * 64 + cc * 8);
                fb[i] = *(const half8*)(lB + (br + i * 16) * 64 + cc * 8);
            }
            #pragma unroll
            for (int mi = 0; mi < 4; ++mi)
                #pragma unroll
                for (int ni = 0; ni < 4; ++ni)
                    acc[mi][ni] = __builtin_amdgcn_mfma_f32_16x16x32_f16(fa[mi], fb[ni], acc[mi][ni], 0, 0, 0);
        }
    }

    // epilogue: bias + activation. Plane uniform per block (128 | 512).
    const int plane = nb >> 2;   // 0=X,1=F,2=O
    const int rq = q * 4;
    const int cl = lane & 15;
    #pragma unroll
    for (int mi = 0; mi < 4; ++mi)
        #pragma unroll
        for (int ni = 0; ni < 4; ++ni) {
            const int gm = m0 + wm + mi * 16 + rq;
            const int gn = n0 + wn + ni * 16 + cl;
            const float bv = bias[gn];
            const int cp = gn & 511;
            #pragma unroll
            for (int r2 = 0; r2 < 4; ++r2) {
                float v = acc[mi][ni][r2] + bv;
                if (plane == 0) {
                    float res = 1.0f - 2.0f / (__expf(2.0f * v) + 1.0f);   // tanh, overflow-safe
                    hu cv; cv.h = (f16)res;
                    X[(size_t)(gm + r2) * Usz + cp] = cv.u;
                } else if (plane == 1) {
                    float res = 1.0f / (1.0f + __expf(-v));                // sigmoid, overflow-safe
                    hu cv; cv.h = (f16)res;
                    F[(size_t)(gm + r2) * Usz + cp] = cv.u;
                } else {
                    float res = 1.0f / (1.0f + __expf(-v));
                    O[(size_t)(gm + r2) * Usz + cp] = res;
                }
            }
        }
}

__device__ __forceinline__ float4_ cvt4(ushort4_ xr) {
    float4_ xv;
    #pragma unroll
    for (int j = 0; j < 4; ++j) { hu cv; cv.u = xr[j]; xv[j] = (float)cv.h; }
    return xv;
}

// ---------- S1: per-chunk composites A=prod f, B=chunk applied to c=0 ----------
// NCH=256 -> 1024 blocks (4/CU, 4 waves/SIMD); next-iter loads prefetched so the
// f/x loads for step i+1 issue before step i's dependent FMA chain (G7).
__global__ __launch_bounds__(256) void scan_chunk(
    const u16* __restrict__ F, const u16* __restrict__ X,
    float* __restrict__ CA, float* __restrict__ CB) {
    int g = blockIdx.x * 256 + threadIdx.x;     // 262144 = B*NCH*U/4
    int u4 = (g & 127) * 4;
    int bc = g >> 7;                             // b*NCH + ch
    size_t base = (size_t)bc * CHL * Usz + u4;
    float4_ c = (float4_)0.0f, A = (float4_)1.0f;
    ushort4_ fcur = *(const ushort4_*)(F + base);
    ushort4_ xcur = *(const ushort4_*)(X + base);
    #pragma unroll
    for (int i = 0; i < CHL; ++i) {
        ushort4_ fnx = fcur, xnx = xcur;
        if (i + 1 < CHL) {
            fnx = *(const ushort4_*)(F + base + (size_t)(i + 1) * Usz);
            xnx = *(const ushort4_*)(X + base + (size_t)(i + 1) * Usz);
        }
        float4_ fv = cvt4(fcur);
        float4_ xv = cvt4(xcur);
        c = fv * c + (1.0f - fv) * xv;
        A = A * fv;
        fcur = fnx; xcur = xnx;
    }
    *(float4_*)(CA + (size_t)bc * Usz + u4) = A;
    *(float4_*)(CB + (size_t)bc * Usz + u4) = c;
}

// ---------- S2: sequential prefix across chunks -> chunk-start carries ----------
// loads are c-independent (address-only) -> unrolled window pipelines them.
__global__ __launch_bounds__(256) void scan_prefix(
    const float* __restrict__ CA, const float* __restrict__ CB,
    float* __restrict__ CS) {
    int g = blockIdx.x * 256 + threadIdx.x;     // 4096 = B*U
    int u = g & 511;
    int b = g >> 9;
    float c = 0.0f;
    #pragma unroll 8
    for (int ch = 0; ch < NCH; ++ch) {
        int idx = (b * NCH + ch) * Usz + u;
        CS[idx] = c;
        c = CA[idx] * c + CB[idx];
    }
}

// ---------- S3: re-scan chunks with carry, h = sigmoid(o)*c (O in-place in out) ----------
__global__ __launch_bounds__(256) void scan_final(
    const u16* __restrict__ F, const u16* __restrict__ X,
    const float* __restrict__ CS, float* __restrict__ out) {
    int g = blockIdx.x * 256 + threadIdx.x;     // 262144
    int u4 = (g & 127) * 4;
    int bc = g >> 7;
    size_t base = (size_t)bc * CHL * Usz + u4;
    float4_ c = *(const float4_*)(CS + (size_t)bc * Usz + u4);
    ushort4_ fcur = *(const ushort4_*)(F + base);
    ushort4_ xcur = *(const ushort4_*)(X + base);
    #pragma unroll
    for (int i = 0; i < CHL; ++i) {
        ushort4_ fnx = fcur, xnx = xcur;
        if (i + 1 < CHL) {
            fnx = *(const ushort4_*)(F + base + (size_t)(i + 1) * Usz);
            xnx = *(const ushort4_*)(X + base + (size_t)(i + 1) * Usz);
        }
        float4_ fv = cvt4(fcur);
        float4_ xv = cvt4(xcur);
        c = fv * c + (1.0f - fv) * xv;
        float4_ ov = *(const float4_*)(out + base + (size_t)i * Usz);  // read O before overwrite
        *(float4_*)(out + base + (size_t)i * Usz) = ov * c;
        fcur = fnx; xcur = xnx;
    }
}

extern "C" void kernel_launch(void* const* d_in, const int* in_sizes, int n_in,
                              void* d_out, int out_size, void* d_ws, size_t ws_size,
                              hipStream_t stream) {
    const float* in   = (const float*)d_in[0];   // [8,4096,512] fp32
    const float* kern = (const float*)d_in[1];   // [2,512,1536] fp32
    const float* bias = (const float*)d_in[2];   // [1536] fp32
    float* out = (float*)d_out;                  // [8,4096,512] fp32
    char* ws = (char*)d_ws;

    // workspace layout (~99 MB; known budget >= 110,102,528)
    const size_t A16_B  = (size_t)Bsz * (Tsz + 1) * Csz * 2;   // 33,562,624
    const size_t OFF_KT = A16_B;
    const size_t OFF_F  = OFF_KT + (size_t)NG * KK * 2;        // 36,708,352
    const size_t OFF_X  = OFF_F + (size_t)MM * Usz * 2;        // 70,262,784
    const size_t NEED   = OFF_X + (size_t)MM * Usz * 2;        // 103,817,216

    if (ws_size < NEED) return;   // guard: fail-with-poison instead of OOB fault

    u16*   A16 = (u16*)ws;
    u16*   KT  = (u16*)(ws + OFF_KT);
    u16*   Fh  = (u16*)(ws + OFF_F);
    u16*   Xb  = (u16*)(ws + OFF_X);
    // scan scratch (12 MB @ NCH=256) aliases the A16 region: A16 is dead once
    // gemm_gates completes, and all launches are stream-ordered (graph replay
    // preserves order; prep_a fully rewrites the region at the start of every replay).
    const size_t CH = (size_t)Bsz * NCH * Usz;   // floats per composite plane
    float* CA = (float*)ws;
    float* CB = CA + CH;
    float* CS = CB + CH;

    prep_a<<<(int)(A16_B / 16 / 256), 256, 0, stream>>>(in, A16);
    prep_k<<<dim3(KK / 64, NG / 64), 256, 0, stream>>>(kern, KT);
    gemm_gates<<<(MM / 128) * (NG / 128), 256, 0, stream>>>(A16, KT, bias, Xb, Fh, out);
    scan_chunk<<<Bsz * NCH * Usz / 4 / 256, 256, 0, stream>>>(Fh, Xb, CA, CB);
    scan_prefix<<<Bsz * Usz / 256, 256, 0, stream>>>(CA, CB, CS);
    scan_final<<<Bsz * NCH * Usz / 4 / 256, 256, 0, stream>>>(Fh, Xb, CS, out);
}

// Round 9
// 290.281 us; speedup vs baseline: 1.2071x; 1.0429x over previous
//
#include <hip/hip_runtime.h>

typedef unsigned short u16;
typedef unsigned int u32;
typedef _Float16 f16;
typedef __attribute__((ext_vector_type(8))) _Float16 half8;
typedef __attribute__((ext_vector_type(2))) __fp16 fp16x2;
typedef __attribute__((ext_vector_type(4))) float float4_;
typedef __attribute__((ext_vector_type(4))) unsigned short ushort4_;
typedef __attribute__((ext_vector_type(4))) unsigned int u32x4;

union hu { f16 h; u16 u; };

__device__ __forceinline__ u32 pkrtz(float a, float b) {
    fp16x2 t = __builtin_amdgcn_cvt_pkrtz(a, b);
    union { fp16x2 h; u32 u; } cv; cv.h = t;
    return cv.u;
}

// ---------- async global->LDS, 16B/lane ----------
__device__ __forceinline__ void gl16(const u16* g, u16* l) {
    __builtin_amdgcn_global_load_lds(
        (const __attribute__((address_space(1))) void*)g,
        (__attribute__((address_space(3))) void*)l, 16, 0, 0);
}

#define Bsz 8
#define Tsz 4096
#define Csz 512
#define Usz 512
#define NG  1536           // 3U
#define KK  1024           // 2 taps * C
#define MM  32768          // B*T
#define NCH 256            // scan chunks (4 blocks/CU in chunk kernels)
#define CHL 16             // chunk length (NCH*CHL = 4096)
#define SEG 16             // chunks per prefix segment
#define NSEG 16            // segments (NSEG*SEG = NCH)

// ---------- P0: inputs fp32 -> fp16 plane [8][4097][512], zero row at t=4096 ----------
__global__ void prep_a(const float* __restrict__ in, u16* __restrict__ A16) {
    int gid = blockIdx.x * 256 + threadIdx.x;       // 2,097,664 threads, 8 halves each
    int idx8 = gid * 8;
    int c8 = idx8 & 511;
    int row = idx8 >> 9;                            // b*4097 + t
    int b = (u32)row / 4097u;
    int t = row - b * 4097;
    u32x4 w;
    if (t == Tsz) {
        w = (u32x4)0;
    } else {
        const float* p = in + ((size_t)(b * Tsz + t) << 9) + c8;
        float4_ v0 = *(const float4_*)p;
        float4_ v1 = *(const float4_*)(p + 4);
        w.x = pkrtz(v0.x, v0.y); w.y = pkrtz(v0.z, v0.w);
        w.z = pkrtz(v1.x, v1.y); w.w = pkrtz(v1.z, v1.w);
    }
    *(u32x4*)(A16 + idx8) = w;
}

// ---------- P1: weights [K=1024][N=1536] fp32 -> transposed fp16 [N][K] ----------
// LDS 64x64 transpose: coalesced fp32 reads, 8B/lane coalesced u16 writes.
__global__ void prep_k(const float* __restrict__ kern, u16* __restrict__ KT) {
    __shared__ u16 t[64][70];                 // 70: spread banks on both phases
    const int k0 = blockIdx.x * 64;           // 16 blocks
    const int n0 = blockIdx.y * 64;           // 24 blocks
    const int tid = threadIdx.x;              // 256
    #pragma unroll
    for (int it = 0; it < 16; ++it) {
        int s = it * 256 + tid;
        int r = s >> 6;                        // k within tile
        int c = s & 63;                        // n within tile (coalesced)
        float v = kern[(size_t)(k0 + r) * NG + n0 + c];
        hu cv; cv.h = (f16)v;                  // RNE
        t[c][r] = cv.u;
    }
    __syncthreads();
    #pragma unroll
    for (int it = 0; it < 4; ++it) {
        int s = it * 256 + tid;
        int n = s >> 4;                        // row of KT tile
        int kq = (s & 15) * 4;                 // 4 u16 per lane, coalesced
        ushort4_ w;
        w.x = t[n][kq]; w.y = t[n][kq + 1]; w.z = t[n][kq + 2]; w.w = t[n][kq + 3];
        *(ushort4_*)(KT + (size_t)(n0 + n) * KK + k0 + kq) = w;
    }
}

// ---------- GEMM (R6/R8-proven core): gates = A'*K', fp16 MFMA, BK=64, XOR-swizzled LDS ----------
// R8 measured: 129.4us, MfmaUtil 37%, VGPR 64, FETCH 85MB, 0 conflicts (~807 TF,
// at the 2-barrier-structure envelope). R7 lesson: (256,5) squeezed VGPR 64->48,
// cost 52% -- bound only to the occupancy you need. Deep-schedule ports lost
// twice (R3/R5) -> retired. DO NOT TOUCH.
__global__ __launch_bounds__(256, 4) void gemm_gates(
    const u16* __restrict__ A16, const u16* __restrict__ KT,
    const float* __restrict__ bias,
    u16* __restrict__ X, u16* __restrict__ F, float* __restrict__ O)
{
    // Tiles [128 rows][64 halves]; 16B chunk c of row r stored at position c ^ (r&7)
    // -> every ds_read_b128 hits the 8-words/bank wave64 floor (0 conflicts, R0/R6/R8).
    __shared__ u16 lA[8192], lB[8192];

    const int tid  = threadIdx.x;
    const int lane = tid & 63;
    const int wave = tid >> 6;

    // bijective XCD swizzle: 3072 wg = 8 XCDs x 384; nb-minor within an XCD so
    // 12 consecutive blocks share one 256KB A tile (L2-hit x12) and KT (3MB)
    // stays L2-resident per XCD. Proven: FETCH 278MB -> 85MB.
    const int orig = blockIdx.x;
    const int wg = (orig & 7) * 384 + (orig >> 3);
    const int nb = wg % 12;
    const int mb = wg / 12;
    const int m0 = mb * 128;
    const int n0 = nb * 128;
    const int b  = m0 >> 12;            // 128 | 4096 -> block never straddles batches
    const int t0 = m0 & 4095;
    const int arow0 = b * (Tsz + 1) + t0;

    float4_ acc[4][4];
    #pragma unroll
    for (int i = 0; i < 4; ++i)
        #pragma unroll
        for (int j = 0; j < 4; ++j) acc[i][j] = (float4_)0.0f;

    const int wm = (wave >> 1) * 64;
    const int wn = (wave & 1) * 64;
    const int ar = wm + (lane & 15);
    const int br = wn + (lane & 15);
    const int q  = lane >> 4;           // k-quad
    const int swz = lane & 7;           // == ar&7 == br&7 (wm,wn multiples of 64)

    for (int kc = 0; kc < KK; kc += 64) {
        __syncthreads();   // protect LDS from previous iteration's readers
        const int tap = kc >> 9;
        const int kin = kc & 511;
        const int ab = arow0 + tap;
        // --- A staging: 128x64 fp16 = 16KB, 4 gl16 iters, XOR-permuted source ---
        #pragma unroll
        for (int it = 0; it < 4; ++it) {
            const int s = it * 256 + tid;          // chunk slot [0,1024)
            const int row = s >> 3, p = s & 7;
            const int c = p ^ (row & 7);
            gl16(A16 + (((size_t)(ab + row)) << 9) + kin + c * 8, lA + (s - lane) * 8);
        }
        // --- B staging: 128x64 fp16 = 16KB ---
        #pragma unroll
        for (int it = 0; it < 4; ++it) {
            const int s = it * 256 + tid;
            const int row = s >> 3, p = s & 7;
            const int c = p ^ (row & 7);
            gl16(KT + (((size_t)(n0 + row)) << 10) + kc + c * 8, lB + (s - lane) * 8);
        }
        __syncthreads();   // staging complete (barrier drains vmcnt)

        #pragma unroll
        for (int s2 = 0; s2 < 2; ++s2) {
            half8 fa[4], fb[4];
            const int cc = (s2 * 4 + q) ^ swz;     // swizzled chunk position
            #pragma unroll
            for (int i = 0; i < 4; ++i) {
                fa[i] = *(const half8*)(lA + (ar + i * 16) * 64 + cc * 8);
                fb[i] = *(const half8*)(lB + (br + i * 16) * 64 + cc * 8);
            }
            #pragma unroll
            for (int mi = 0; mi < 4; ++mi)
                #pragma unroll
                for (int ni = 0; ni < 4; ++ni)
                    acc[mi][ni] = __builtin_amdgcn_mfma_f32_16x16x32_f16(fa[mi], fb[ni], acc[mi][ni], 0, 0, 0);
        }
    }

    // epilogue: bias + activation. Plane uniform per block (128 | 512).
    const int plane = nb >> 2;   // 0=X,1=F,2=O
    const int rq = q * 4;
    const int cl = lane & 15;
    #pragma unroll
    for (int mi = 0; mi < 4; ++mi)
        #pragma unroll
        for (int ni = 0; ni < 4; ++ni) {
            const int gm = m0 + wm + mi * 16 + rq;
            const int gn = n0 + wn + ni * 16 + cl;
            const float bv = bias[gn];
            const int cp = gn & 511;
            #pragma unroll
            for (int r2 = 0; r2 < 4; ++r2) {
                float v = acc[mi][ni][r2] + bv;
                if (plane == 0) {
                    float res = 1.0f - 2.0f / (__expf(2.0f * v) + 1.0f);   // tanh, overflow-safe
                    hu cv; cv.h = (f16)res;
                    X[(size_t)(gm + r2) * Usz + cp] = cv.u;
                } else if (plane == 1) {
                    float res = 1.0f / (1.0f + __expf(-v));                // sigmoid, overflow-safe
                    hu cv; cv.h = (f16)res;
                    F[(size_t)(gm + r2) * Usz + cp] = cv.u;
                } else {
                    float res = 1.0f / (1.0f + __expf(-v));
                    O[(size_t)(gm + r2) * Usz + cp] = res;
                }
            }
        }
}

__device__ __forceinline__ float4_ cvt4(ushort4_ xr) {
    float4_ xv;
    #pragma unroll
    for (int j = 0; j < 4; ++j) { hu cv; cv.u = xr[j]; xv[j] = (float)cv.h; }
    return xv;
}

// ---------- S1: per-chunk composites A=prod f, B=chunk applied to c=0 ----------
// NCH=256 -> 1024 blocks (4/CU); next-iter loads prefetched (G7).
__global__ __launch_bounds__(256) void scan_chunk(
    const u16* __restrict__ F, const u16* __restrict__ X,
    float* __restrict__ CA, float* __restrict__ CB) {
    int g = blockIdx.x * 256 + threadIdx.x;     // 262144 = B*NCH*U/4
    int u4 = (g & 127) * 4;
    int bc = g >> 7;                             // b*NCH + ch
    size_t base = (size_t)bc * CHL * Usz + u4;
    float4_ c = (float4_)0.0f, A = (float4_)1.0f;
    ushort4_ fcur = *(const ushort4_*)(F + base);
    ushort4_ xcur = *(const ushort4_*)(X + base);
    #pragma unroll
    for (int i = 0; i < CHL; ++i) {
        ushort4_ fnx = fcur, xnx = xcur;
        if (i + 1 < CHL) {
            fnx = *(const ushort4_*)(F + base + (size_t)(i + 1) * Usz);
            xnx = *(const ushort4_*)(X + base + (size_t)(i + 1) * Usz);
        }
        float4_ fv = cvt4(fcur);
        float4_ xv = cvt4(xcur);
        c = fv * c + (1.0f - fv) * xv;
        A = A * fv;
        fcur = fnx; xcur = xnx;
    }
    *(float4_*)(CA + (size_t)bc * Usz + u4) = A;
    *(float4_*)(CB + (size_t)bc * Usz + u4) = c;
}

// ---------- S2 hierarchical prefix (R8 post-mortem: old scan_prefix ran on
// 16 blocks = 16 CUs, per-CU BW-limited ~15-30us). Compose rule:
// (A1,B1) then (A2,B2) = (A2*A1, A2*B1 + B2). All three stages fully parallel.
// S2a: per-(b,u,seg) segment composite over SEG chunks. 65536 thr, 256 blocks.
__global__ __launch_bounds__(256) void scan_seg(
    const float* __restrict__ CA, const float* __restrict__ CB,
    float* __restrict__ SA, float* __restrict__ SB) {
    int g = blockIdx.x * 256 + threadIdx.x;     // 65536 = B*NSEG*U
    int u = g & 511;
    int t2 = g >> 9;
    int s = t2 & (NSEG - 1);
    int b = t2 >> 4;
    float A = 1.0f, Bv = 0.0f;
    #pragma unroll
    for (int k = 0; k < SEG; ++k) {
        int idx = (b * NCH + s * SEG + k) * Usz + u;
        float a = CA[idx], bb = CB[idx];
        Bv = a * Bv + bb;
        A  = a * A;
    }
    int o = (b * NSEG + s) * Usz + u;
    SA[o] = A; SB[o] = Bv;
}

// S2b: 16-step prefix across segments per (b,u) -> segment-start carries CSS.
// 4096 thr; only 16 iterations and 0.5MB traffic (was 256 iters / 12.6MB).
__global__ __launch_bounds__(256) void scan_segpfx(
    const float* __restrict__ SA, const float* __restrict__ SB,
    float* __restrict__ CSS) {
    int g = blockIdx.x * 256 + threadIdx.x;     // 4096 = B*U
    int u = g & 511;
    int b = g >> 9;
    float c = 0.0f;
    #pragma unroll
    for (int s = 0; s < NSEG; ++s) {
        int o = (b * NSEG + s) * Usz + u;
        CSS[o] = c;
        c = SA[o] * c + SB[o];
    }
}

// S2c: expand segment carries to chunk-start carries CS (same output as the old
// scan_prefix). 65536 thr, 256 blocks.
__global__ __launch_bounds__(256) void scan_expand(
    const float* __restrict__ CA, const float* __restrict__ CB,
    const float* __restrict__ CSS, float* __restrict__ CS) {
    int g = blockIdx.x * 256 + threadIdx.x;     // 65536 = B*NSEG*U
    int u = g & 511;
    int t2 = g >> 9;
    int s = t2 & (NSEG - 1);
    int b = t2 >> 4;
    float c = CSS[(b * NSEG + s) * Usz + u];
    #pragma unroll
    for (int k = 0; k < SEG; ++k) {
        int idx = (b * NCH + s * SEG + k) * Usz + u;
        CS[idx] = c;
        c = CA[idx] * c + CB[idx];
    }
}

// ---------- S3: re-scan chunks with carry, h = sigmoid(o)*c (O in-place in out) ----------
__global__ __launch_bounds__(256) void scan_final(
    const u16* __restrict__ F, const u16* __restrict__ X,
    const float* __restrict__ CS, float* __restrict__ out) {
    int g = blockIdx.x * 256 + threadIdx.x;     // 262144
    int u4 = (g & 127) * 4;
    int bc = g >> 7;
    size_t base = (size_t)bc * CHL * Usz + u4;
    float4_ c = *(const float4_*)(CS + (size_t)bc * Usz + u4);
    ushort4_ fcur = *(const ushort4_*)(F + base);
    ushort4_ xcur = *(const ushort4_*)(X + base);
    #pragma unroll
    for (int i = 0; i < CHL; ++i) {
        ushort4_ fnx = fcur, xnx = xcur;
        if (i + 1 < CHL) {
            fnx = *(const ushort4_*)(F + base + (size_t)(i + 1) * Usz);
            xnx = *(const ushort4_*)(X + base + (size_t)(i + 1) * Usz);
        }
        float4_ fv = cvt4(fcur);
        float4_ xv = cvt4(xcur);
        c = fv * c + (1.0f - fv) * xv;
        float4_ ov = *(const float4_*)(out + base + (size_t)i * Usz);  // read O before overwrite
        *(float4_*)(out + base + (size_t)i * Usz) = ov * c;
        fcur = fnx; xcur = xnx;
    }
}

extern "C" void kernel_launch(void* const* d_in, const int* in_sizes, int n_in,
                              void* d_out, int out_size, void* d_ws, size_t ws_size,
                              hipStream_t stream) {
    const float* in   = (const float*)d_in[0];   // [8,4096,512] fp32
    const float* kern = (const float*)d_in[1];   // [2,512,1536] fp32
    const float* bias = (const float*)d_in[2];   // [1536] fp32
    float* out = (float*)d_out;                  // [8,4096,512] fp32
    char* ws = (char*)d_ws;

    // workspace layout (~99 MB; known budget >= 110,102,528)
    const size_t A16_B  = (size_t)Bsz * (Tsz + 1) * Csz * 2;   // 33,562,624
    const size_t OFF_KT = A16_B;
    const size_t OFF_F  = OFF_KT + (size_t)NG * KK * 2;        // 36,708,352
    const size_t OFF_X  = OFF_F + (size_t)MM * Usz * 2;        // 70,262,784
    const size_t NEED   = OFF_X + (size_t)MM * Usz * 2;        // 103,817,216

    if (ws_size < NEED) return;   // guard: fail-with-poison instead of OOB fault

    u16*   A16 = (u16*)ws;
    u16*   KT  = (u16*)(ws + OFF_KT);
    u16*   Fh  = (u16*)(ws + OFF_F);
    u16*   Xb  = (u16*)(ws + OFF_X);
    // scan scratch (13.4 MB) aliases the A16 region (33.5 MB): A16 is dead once
    // gemm_gates completes, and all launches are stream-ordered (graph replay
    // preserves order; prep_a fully rewrites the region at the start of every replay).
    const size_t CH  = (size_t)Bsz * NCH * Usz;    // floats per chunk-composite plane
    const size_t CHS = (size_t)Bsz * NSEG * Usz;   // floats per segment plane
    float* CA  = (float*)ws;
    float* CB  = CA + CH;
    float* CS  = CB + CH;
    float* SA  = CS + CH;
    float* SB  = SA + CHS;
    float* CSS = SB + CHS;

    prep_a<<<(int)(A16_B / 16 / 256), 256, 0, stream>>>(in, A16);
    prep_k<<<dim3(KK / 64, NG / 64), 256, 0, stream>>>(kern, KT);
    gemm_gates<<<(MM / 128) * (NG / 128), 256, 0, stream>>>(A16, KT, bias, Xb, Fh, out);
    scan_chunk<<<Bsz * NCH * Usz / 4 / 256, 256, 0, stream>>>(Fh, Xb, CA, CB);
    scan_seg<<<Bsz * NSEG * Usz / 256, 256, 0, stream>>>(CA, CB, SA, SB);
    scan_segpfx<<<Bsz * Usz / 256, 256, 0, stream>>>(SA, SB, CSS);
    scan_expand<<<Bsz * NSEG * Usz / 256, 256, 0, stream>>>(CA, CB, CSS, CS);
    scan_final<<<Bsz * NCH * Usz / 4 / 256, 256, 0, stream>>>(Fh, Xb, CS, out);
}